// Round 2
// baseline (1436.593 us; speedup 1.0000x reference)
//
#include <hip/hip_runtime.h>

#define BATCH 256
#define TSTEPS 2048
#define NDIM 64
#define DIN 6
#define ALPHA 0.2f
// sqrt(2 * 0.2 * 0.15^2)
#define NSCALE 0.09486832980505137f

// R6: 4-wave cooperative scan + fused output projection, one kernel.
//
// The R5 single-wave kernel was VALU-issue-bound on one SIMD (~150 VALU
// ops/step, VALUBusy 18.6% = ~75% of one of the CU's 4 SIMDs) while 3 SIMDs
// idled, and the separate out_proj kernel cost ~186 us of the 698 us total.
//
// Split: the validated kernel computes each output as 4 chains over column
// classes i%4 == 0..3 combined as ((ax+ay)+(az+aw))+d. Wave w now owns chain
// class w: 16 readlane + 16 fma per step, partial -> LDS, s_barrier, all
// waves read the 4 partials and REDUNDANTLY compute the identical combine +
// blend (same fmaf ops, same order => states trajectory is BIT-IDENTICAL to
// the harness-validated R4/R5 kernels). Wave 0 stores states; waves 1/2 each
// reduce one W_out row via shfl_xor and burst-store out every 8 steps.
//
// Sync: raw s_barrier + explicit "s_waitcnt lgkmcnt(0)" (asm with memory
// clobber) before it, and an empty memory-clobber asm after it so the
// compiler cannot hoist the partial reads above the barrier. NOT
// __syncthreads(): its vmcnt(0) drain would stall on the 20 in-flight
// prefetch loads every 8 steps. Double-buffered partials (parity p) make the
// single barrier per step race-free: writes at step t+1 target the opposite
// buffer from reads at step t, and no wave can be 2 steps ahead.
__device__ __forceinline__ float rdlane(float v, int lane) {
    return __uint_as_float((unsigned)__builtin_amdgcn_readlane((int)__float_as_uint(v), lane));
}

__global__ __launch_bounds__(256, 1) void rnn_fused_kernel(
    const float* __restrict__ u,      // [B, T, DIN]
    const float* __restrict__ noise,  // [B, T, N]
    const float* __restrict__ W_rec,  // [N, N]
    const float* __restrict__ W_in,   // [N, DIN]
    const float* __restrict__ W_out,  // [2, N]
    float* __restrict__ states,       // [B, T, N]
    float* __restrict__ out)          // [B, T, 2]
{
    const int b = blockIdx.x;
    const int tid = threadIdx.x;
    const int w = tid >> 6;   // wave 0..3 = chain class
    const int j = tid & 63;   // lane = output element

    __shared__ float part[2][4][NDIM];  // [parity][wave][element]

    // Chain-class-w weights of row j: wc[k] = W_rec[j][4k+w], k ascending —
    // exactly the term order of the validated ax/ay/az/aw chains.
    float wc[16];
#pragma unroll
    for (int k = 0; k < 16; ++k) wc[k] = W_rec[j * NDIM + 4 * k + w];

    float win[DIN];
#pragma unroll
    for (int d = 0; d < DIN; ++d) win[d] = W_in[j * DIN + d];

    float wo = 0.0f;
    if (w == 1) wo = W_out[j];             // out channel 0
    else if (w == 2) wo = W_out[NDIM + j]; // out channel 1

    const float* nb = noise + (size_t)b * TSTEPS * NDIM;
    const float4* ub4 = reinterpret_cast<const float4*>(u + (size_t)b * TSTEPS * DIN);
    float* st = states + (size_t)b * TSTEPS * NDIM;
    float* ob = out + (size_t)b * TSTEPS * 2;

    float s = 0.0f;
    if (w == 0) st[j] = 0.0f;                         // states[b,0,:] = 0
    if ((w == 1 || w == 2) && j == 0) ob[w - 1] = 0.0f;  // out[b,0,:] = 0

    int p = 0;          // partial-buffer parity
    float prb[8];       // projection stash (statically indexed only)

    // One recurrence step. k8 is the compile-time step index within a run8
    // body (static prb index — rule #20).
    auto step_body = [&](int t, float nvk, const float* uuf, int k8) {
        // Own chain class: a_w[j] = sum_k W[j][4k+w] * s[4k+w], sequential.
        float a = 0.0f;
#pragma unroll
        for (int k = 0; k < 16; ++k) {
            a = fmaf(wc[k], rdlane(s, 4 * k + w), a);
        }
        // Drive (identical to validated kernel)
        float d = NSCALE * nvk;
#pragma unroll
        for (int kk = 0; kk < DIN; ++kk) d = fmaf(win[kk], uuf[kk], d);

        part[p][w][j] = a;
        asm volatile("s_waitcnt lgkmcnt(0)" ::: "memory");  // write visible
        __builtin_amdgcn_s_barrier();
        asm volatile("" ::: "memory");  // no hoisting reads above barrier
        const float a0 = part[p][0][j];
        const float a1 = part[p][1][j];
        const float a2 = part[p][2][j];
        const float a3 = part[p][3][j];
        const float acc = ((a0 + a1) + (a2 + a3)) + d;
        s = fmaf(1.0f - ALPHA, s, ALPHA * fmaxf(acc, 0.0f));
        p ^= 1;

        if (w == 0) {
            st[(size_t)(t + 1) * NDIM + j] = s;  // fire-and-forget
        } else if (w == 1 || w == 2) {
            // Projection: full-wave reduce; every lane ends with the sum.
            float pr = wo * s;
            pr += __shfl_xor(pr, 1);
            pr += __shfl_xor(pr, 2);
            pr += __shfl_xor(pr, 4);
            pr += __shfl_xor(pr, 8);
            pr += __shfl_xor(pr, 16);
            pr += __shfl_xor(pr, 32);
            prb[k8] = pr;  // store deferred: keeps shuffle latency off pace
        }
    };

    // Prefetch buffers: 8 steps of noise (per-lane dword) and u (wave-uniform,
    // 12 float4). A/B ping-pong, guard-free. All 4 waves load the same
    // noise/u lines (shared per-CU L1 -> no extra HBM fetch).
    float nva[8], nvb[8];
    float4 uua[12], uub[12];
#pragma unroll
    for (int k = 0; k < 8; ++k) nva[k] = nb[k * NDIM + j];
#pragma unroll
    for (int k = 0; k < 12; ++k) uua[k] = ub4[k];

    // 8 guard-free steps from (nv,uu) while prefetching tb+8..tb+15 into
    // (nvN,uuN); then burst-store the 8 stashed projections.
    auto run8 = [&](int tb, const float* nv, const float4* uu,
                    float* nvN, float4* uuN) {
        const int tpf = tb + 8;
#pragma unroll
        for (int k = 0; k < 8; ++k) nvN[k] = nb[(tpf + k) * NDIM + j];
        const int ubase = tpf * DIN / 4;  // tpf multiple of 8 -> exact
#pragma unroll
        for (int k = 0; k < 12; ++k) uuN[k] = ub4[ubase + k];

        const float* uuf = reinterpret_cast<const float*>(uu);
#pragma unroll
        for (int k = 0; k < 8; ++k) step_body(tb + k, nv[k], uuf + k * DIN, k);

        if ((w == 1 || w == 2) && j == 0) {
#pragma unroll
            for (int k = 0; k < 8; ++k)
                ob[(size_t)(tb + 1 + k) * 2 + (w - 1)] = prb[k];
        }
    };

    // T-1 = 2047 steps: 127*16 (ping-pong pairs) + 8 + 7-step tail.
    int tb = 0;
    for (int it = 0; it < 127; ++it) {
        run8(tb, nva, uua, nvb, uub); tb += 8;   // uses A, refills B
        run8(tb, nvb, uub, nva, uua); tb += 8;   // uses B, refills A
    }
    // tb == 2032; A holds 2032..2039. Prefetch 2040..2047 into B (in-bounds).
    run8(2032, nva, uua, nvb, uub);
    // Tail: steps 2040..2046 (7 steps) from B, no further prefetch.
    {
        const float* uuf = reinterpret_cast<const float*>(uub);
#pragma unroll
        for (int k = 0; k < 7; ++k) step_body(2040 + k, nvb[k], uuf + k * DIN, k);
        if ((w == 1 || w == 2) && j == 0) {
#pragma unroll
            for (int k = 0; k < 7; ++k)
                ob[(size_t)(2041 + k) * 2 + (w - 1)] = prb[k];
        }
    }
}

extern "C" void kernel_launch(void* const* d_in, const int* in_sizes, int n_in,
                              void* d_out, int out_size, void* d_ws, size_t ws_size,
                              hipStream_t stream) {
    const float* u     = (const float*)d_in[0];
    const float* noise = (const float*)d_in[1];
    const float* W_rec = (const float*)d_in[2];
    const float* W_in  = (const float*)d_in[3];
    const float* W_out = (const float*)d_in[4];

    float* states = (float*)d_out;                           // B*T*N floats
    float* out    = states + (size_t)BATCH * TSTEPS * NDIM;  // B*T*2 floats

    rnn_fused_kernel<<<BATCH, 256, 0, stream>>>(u, noise, W_rec, W_in, W_out,
                                                states, out);
}